// Round 12
// baseline (224.505 us; speedup 1.0000x reference)
//
#include <hip/hip_runtime.h>

typedef _Float16 f16;
typedef _Float16 f16x8 __attribute__((ext_vector_type(8)));
typedef _Float16 f16x4 __attribute__((ext_vector_type(4)));
typedef float f32x4 __attribute__((ext_vector_type(4)));

static constexpr int Bn = 2, Tn = 2048, Hn = 1024, NHn = 16, HDn = 64, HALFn = 32;
static constexpr int Mn = Bn * Tn;     // 4096
static constexpr int Kn = Hn;          // 1024
static constexpr int Nqkv = 3 * Hn;    // 3072

// async global->LDS, 16B per lane; dest must be linear-in-lane (rule #21)
__device__ __forceinline__ void gl16(const f16* g, f16* l) {
  __builtin_amdgcn_global_load_lds(
      (const __attribute__((address_space(1))) void*)g,
      (__attribute__((address_space(3))) void*)l, 16, 0, 0);
}

// ---------------- kernel: f32 -> f16 convert (vectorized, unchanged) --------
__global__ void k_convert(const float* __restrict__ in, f16* __restrict__ out, int n4) {
  int i = blockIdx.x * blockDim.x + threadIdx.x;
  if (i >= n4) return;
  float4 v = ((const float4*)in)[i];
  f16x4 o = { (f16)v.x, (f16)v.y, (f16)v.z, (f16)v.w };
  ((f16x4*)out)[i] = o;
}

// ------- transpose+convert W[Kr][Nc] f32 -> WT[Nc][Kr] f16 (unchanged) ------
__global__ void k_transpose(const float* __restrict__ W, f16* __restrict__ WT,
                            int Nc, int Kr) {
  const int wave = threadIdx.x >> 6, lane = threadIdx.x & 63;
  const int n  = blockIdx.x * 32 + wave * 8 + (lane >> 3);
  const int k0 = blockIdx.y * 64 + (lane & 7) * 8;
  f16x8 v;
#pragma unroll
  for (int j = 0; j < 8; ++j) v[j] = (f16)W[(size_t)(k0 + j) * Nc + n];
  *(f16x8*)(WT + (size_t)n * Kr + k0) = v;
}

// ---------------- GEMM (unchanged from round 7) ------------------------------
template <int EPI>
__global__ __launch_bounds__(256) void k_gemm(
    const f16* __restrict__ A, const f16* __restrict__ BT,
    const float* __restrict__ rc, const float* __restrict__ rs,
    const float* __restrict__ bias,
    f16* __restrict__ qo, f16* __restrict__ ko, f16* __restrict__ vto,
    float* __restrict__ out, int Kd) {
  __shared__ f16 smem[16384];          // Af 128x64 | Bf 128x64 (32 KB)
  f16* Af = smem;
  f16* Bf = smem + 8192;
  const int tid = threadIdx.x;
  const int wave = tid >> 6, lane = tid & 63;
  const int lr = lane & 15, lg = lane >> 4;
  const int m0 = blockIdx.x * 128, n0 = blockIdx.y * 128;
  const int wm = (wave & 1) * 64, wn = (wave >> 1) * 64;
  const int lane8 = lane >> 3;         // row within 8-row staging group
  const int sc = lane & 7;             // linear dest 16B chunk

  f32x4 acc[4][4] = {};

  for (int k0 = 0; k0 < Kd; k0 += 64) {
    __syncthreads();
#pragma unroll
    for (int i = 0; i < 4; ++i) {
      int r = wave * 32 + i * 8 + lane8;
      int csrc = sc ^ (r & 7);         // pre-swizzled global chunk
      gl16(A  + (size_t)(m0 + r) * Kd + k0 + csrc * 8, Af + r * 64 + sc * 8);
      gl16(BT + (size_t)(n0 + r) * Kd + k0 + csrc * 8, Bf + r * 64 + sc * 8);
    }
    __syncthreads();                   // drains vmcnt(0): LDS tiles ready
#pragma unroll
    for (int kf = 0; kf < 2; ++kf) {
      f16x8 af[4], bf[4];
#pragma unroll
      for (int mi = 0; mi < 4; ++mi) {
        int row = wm + mi * 16 + lr;
        af[mi] = *(const f16x8*)(Af + row * 64 + (((kf * 4 + lg) ^ (row & 7)) * 8));
      }
#pragma unroll
      for (int ni = 0; ni < 4; ++ni) {
        int row = wn + ni * 16 + lr;
        bf[ni] = *(const f16x8*)(Bf + row * 64 + (((kf * 4 + lg) ^ (row & 7)) * 8));
      }
#pragma unroll
      for (int mi = 0; mi < 4; ++mi)
#pragma unroll
        for (int ni = 0; ni < 4; ++ni)
          acc[mi][ni] = __builtin_amdgcn_mfma_f32_16x16x32_f16(af[mi], bf[ni], acc[mi][ni], 0, 0, 0);
    }
  }

  if (EPI == 1) {
#pragma unroll
    for (int mi = 0; mi < 4; ++mi)
#pragma unroll
      for (int ni = 0; ni < 4; ++ni) {
        int col = n0 + wn + ni * 16 + lr;
        float bv = bias[col];
#pragma unroll
        for (int r = 0; r < 4; ++r) {
          int grow = m0 + wm + mi * 16 + lg * 4 + r;
          out[(size_t)grow * Hn + col] = acc[mi][ni][r] + bv;
        }
      }
    return;
  }

  const int part = n0 >> 10;
  if (part < 2) {
    f16* dst = (part == 0) ? qo : ko;
    const float scale = (part == 0) ? 0.125f : 1.0f;  // HD^-0.5 folded into q
#pragma unroll
    for (int mi = 0; mi < 4; ++mi)
#pragma unroll
      for (int ni = 0; ni < 4; ++ni) {
        int col = n0 + wn + ni * 16 + lr;
        int hn = (col >> 6) & 15, d = col & 63;
#pragma unroll
        for (int r = 0; r < 4; ++r) {
          int grow = m0 + wm + mi * 16 + lg * 4 + r;
          int b = grow >> 11, t = grow & (Tn - 1);
          float v = acc[mi][ni][r];
          float vp = __shfl_xor(v, 1);  // partner column (d^1) lives in lane^1
          float cc = rc[t * HALFn + (d >> 1)];
          float ss = rs[t * HALFn + (d >> 1)];
          float res = (d & 1) ? (ss * vp + cc * v) : (cc * v - ss * vp);
          res *= scale;
          dst[(((size_t)(b * NHn + hn)) * Tn + t) * HDn + d] = (f16)res;
        }
      }
  } else {
    // V: write transposed [b,h,d,t] via LDS bounce
    __syncthreads();
#pragma unroll
    for (int mi = 0; mi < 4; ++mi)
#pragma unroll
      for (int ni = 0; ni < 4; ++ni) {
        int dl = wn + ni * 16 + lr;
#pragma unroll
        for (int r = 0; r < 4; ++r) {
          int tl = wm + mi * 16 + lg * 4 + r;
          smem[tl * 128 + dl] = (f16)acc[mi][ni][r];
        }
      }
    __syncthreads();
    int b = m0 >> 11, t0 = m0 & (Tn - 1);
    int hbase = (n0 & 1023) >> 6;
#pragma unroll
    for (int it = 0; it < 8; ++it) {
      int slot = tid + it * 256;
      int d = slot >> 4, tc = slot & 15;
      f16x8 v;
#pragma unroll
      for (int j = 0; j < 8; ++j) v[j] = smem[(tc * 8 + j) * 128 + d];
      int hh = hbase + (d >> 6), dc = d & 63;
      *(f16x8*)(vto + (((size_t)(b * NHn + hh)) * HDn + dc) * Tn + t0 + tc * 8) = v;
    }
  }
}

// ---------------- flash attention: 16 q-rows/wave, 2x occupancy --------------
// grid (T/64, B*NH) = 1024 blocks (4/CU, 16 waves/CU vs old 8). Per wave: one
// 16-q tile (qf[2], s[4], o[4], scalar m/l). KV staging/barriers unchanged.
__global__ __launch_bounds__(256) void k_attn(
    const f16* __restrict__ Q, const f16* __restrict__ Kk,
    const f16* __restrict__ VT, f16* __restrict__ O) {
  __shared__ f16 Kl[64 * 64];
  __shared__ f16 Vl[64 * 64];     // V^T tile: [d][kv]
  __shared__ f16 Pl[4][16 * 64];  // per-wave P [q][kv]; reused as O-bounce [q][d]
  const int tid = threadIdx.x;
  const int wave = tid >> 6, lane = tid & 63;
  const int lr = lane & 15, lg = lane >> 4;
  const int bh = blockIdx.y;
  const int q0 = blockIdx.x * 64;
  const f16* qb = Q + (size_t)bh * (Tn * HDn);
  const f16* kb = Kk + (size_t)bh * (Tn * HDn);
  const f16* vb = VT + (size_t)bh * (HDn * Tn);
  f16* Pw = Pl[wave];

  // Q as B-operand (col=q=lr, k=d)
  f16x8 qf[2];
#pragma unroll
  for (int h = 0; h < 2; ++h)
    qf[h] = *(const f16x8*)(qb + (size_t)(q0 + wave * 16 + lr) * HDn + h * 32 + lg * 8);

  f32x4 o[4] = {};             // O^T: row d=di*16+lg*4+r, col q=lr
  float m = -1e30f;
  float l = 0.f;               // lane-partial row sum (reduced across lg at end)

  for (int kt = 0; kt < Tn / 64; ++kt) {
    __syncthreads();
#pragma unroll
    for (int it = 0; it < 2; ++it) {
      int slot = tid + it * 256;
      int row = slot >> 3, c = slot & 7;
      f16x8 kv = *(const f16x8*)(kb + (size_t)(kt * 64 + row) * HDn + c * 8);
      f16x8 vv = *(const f16x8*)(vb + (size_t)row * Tn + kt * 64 + c * 8);
      *(f16x8*)(Kl + row * 64 + ((c ^ (row & 7)) * 8)) = kv;
      *(f16x8*)(Vl + row * 64 + ((c ^ (row & 7)) * 8)) = vv;
    }
    __syncthreads();

    // S^T = K Q^T (row=kv, col=q); q pre-scaled by 1/8 in k_gemm<0>
    f32x4 s[4];
#pragma unroll
    for (int kvi = 0; kvi < 4; ++kvi) {
      int row = kvi * 16 + lr;
      f16x8 kf0 = *(const f16x8*)(Kl + row * 64 + ((lg ^ (row & 7)) * 8));
      f16x8 kf1 = *(const f16x8*)(Kl + row * 64 + (((4 + lg) ^ (row & 7)) * 8));
      f32x4 t = {0.f, 0.f, 0.f, 0.f};
      t = __builtin_amdgcn_mfma_f32_16x16x32_f16(kf0, qf[0], t, 0, 0, 0);
      t = __builtin_amdgcn_mfma_f32_16x16x32_f16(kf1, qf[1], t, 0, 0, 0);
      s[kvi] = t;
    }

    // defer-max online softmax: in-thread tile max, rescale only when it grows
    f32x4 m4 = s[0];
#pragma unroll
    for (int kvi = 1; kvi < 4; ++kvi) {
      m4[0] = fmaxf(m4[0], s[kvi][0]); m4[1] = fmaxf(m4[1], s[kvi][1]);
      m4[2] = fmaxf(m4[2], s[kvi][2]); m4[3] = fmaxf(m4[3], s[kvi][3]);
    }
    float pm = fmaxf(fmaxf(m4[0], m4[1]), fmaxf(m4[2], m4[3]));
    if (!__all(pm <= m + 8.f)) {
      float mx = pm;
      mx = fmaxf(mx, __shfl_xor(mx, 16));
      mx = fmaxf(mx, __shfl_xor(mx, 32));
      float mnew = fmaxf(m, mx);
      float alpha = __expf(m - mnew);
      m = mnew;
      l *= alpha;
#pragma unroll
      for (int di = 0; di < 4; ++di) {
        o[di][0] *= alpha; o[di][1] *= alpha;
        o[di][2] *= alpha; o[di][3] *= alpha;
      }
    }

    // exp + partial row sum + packed P write (8B words, kv contiguous over r)
    {
      int q = lr;
      float rsum = 0.f;
#pragma unroll
      for (int kvi = 0; kvi < 4; ++kvi) {
        f16x4 w;
#pragma unroll
        for (int r = 0; r < 4; ++r) {
          float p = __expf(s[kvi][r] - m);
          rsum += p;
          w[r] = (f16)p;
        }
        int byteoff = (kvi * 32 + lg * 8) ^ ((q & 7) << 4);
        *(f16x4*)(Pw + q * 64 + (byteoff >> 1)) = w;
      }
      l += rsum;
    }

    // O^T += V^T · P  (A = V^T rows d, B = P col q, K = kv)
#pragma unroll
    for (int h = 0; h < 2; ++h) {
      f16x8 pb, va[4];
      {
        int q = lr;
        int byteoff = (h * 64 + lg * 16) ^ ((q & 7) << 4);
        pb = *(const f16x8*)(Pw + q * 64 + (byteoff >> 1));
      }
#pragma unroll
      for (int di = 0; di < 4; ++di) {
        int row = di * 16 + lr;
        va[di] = *(const f16x8*)(Vl + row * 64 + (((h * 4 + lg) ^ (row & 7)) * 8));
      }
#pragma unroll
      for (int di = 0; di < 4; ++di)
        o[di] = __builtin_amdgcn_mfma_f32_16x16x32_f16(va[di], pb, o[di], 0, 0, 0);
    }
  }

  // finalize: reduce lane-partial l across lg, scale, transpose via LDS bounce
  float lf = l;
  lf += __shfl_xor(lf, 16);
  lf += __shfl_xor(lf, 32);
  float inv = 1.f / lf;
  {
    int q = lr;
#pragma unroll
    for (int di = 0; di < 4; ++di) {
      f16x4 w;
#pragma unroll
      for (int r = 0; r < 4; ++r) w[r] = (f16)(o[di][r] * inv);
      int byteoff = (di * 32 + lg * 8) ^ ((q & 7) << 4);
      *(f16x4*)(Pw + q * 64 + (byteoff >> 1)) = w;
    }
  }
  const int b = bh >> 4, h = bh & 15;
#pragma unroll
  for (int it = 0; it < 2; ++it) {
    int row = it * 8 + (lane >> 3);   // local q 0..15
    int c = lane & 7;                 // 16B chunk of the 64-d row
    int byteoff = (c * 16) ^ ((row & 7) << 4);
    f16x8 v = *(const f16x8*)(Pw + row * 64 + (byteoff >> 1));
    int t = q0 + wave * 16 + row;
    *(f16x8*)(O + ((size_t)(b * Tn + t)) * Hn + h * HDn + c * 8) = v;
  }
}

// ---------------- launch ----------------------------------------------------
extern "C" void kernel_launch(void* const* d_in, const int* in_sizes, int n_in,
                              void* d_out, int out_size, void* d_ws, size_t ws_size,
                              hipStream_t stream) {
  const float* x     = (const float*)d_in[0];
  const float* wqkv  = (const float*)d_in[1];
  const float* wproj = (const float*)d_in[2];
  const float* bproj = (const float*)d_in[3];
  const float* rc    = (const float*)d_in[4];
  const float* rs    = (const float*)d_in[5];
  float* out = (float*)d_out;

  char* ws = (char*)d_ws;
  f16* Xh  = (f16*)(ws);                    // 8 MB  [4096][1024]
  f16* WqT = (f16*)(ws + (8u << 20));       // 6 MB  [3072][1024]
  f16* WpT = (f16*)(ws + (14u << 20));      // 2 MB  [1024][1024]
  f16* Qw  = (f16*)(ws + (16u << 20));      // 8 MB  [32][2048][64]
  f16* Kw  = (f16*)(ws + (24u << 20));      // 8 MB
  f16* Vw  = (f16*)(ws + (32u << 20));      // 8 MB  [32][64][2048]  (transposed)
  f16* Ao  = (f16*)(ws + (40u << 20));      // 8 MB  [4096][1024]

  k_convert<<<(Mn * Kn / 4 + 255) / 256, 256, 0, stream>>>(x, Xh, Mn * Kn / 4);
  k_transpose<<<dim3(Nqkv / 32, Kn / 64), 256, 0, stream>>>(wqkv, WqT, Nqkv, Kn);
  k_transpose<<<dim3(Hn / 32, Kn / 64), 256, 0, stream>>>(wproj, WpT, Hn, Kn);
  k_gemm<0><<<dim3(Mn / 128, Nqkv / 128), 256, 0, stream>>>(
      Xh, WqT, rc, rs, nullptr, Qw, Kw, Vw, nullptr, Kn);
  k_attn<<<dim3(Tn / 64, Bn * NHn), 256, 0, stream>>>(Qw, Kw, Vw, Ao);
  k_gemm<1><<<dim3(Mn / 128, Hn / 128), 256, 0, stream>>>(
      Ao, WpT, nullptr, nullptr, bproj, nullptr, nullptr, nullptr, out, Kn);
}

// Round 13
// 214.287 us; speedup vs baseline: 1.0477x; 1.0477x over previous
//
#include <hip/hip_runtime.h>

typedef _Float16 f16;
typedef _Float16 f16x8 __attribute__((ext_vector_type(8)));
typedef _Float16 f16x4 __attribute__((ext_vector_type(4)));
typedef float f32x4 __attribute__((ext_vector_type(4)));

static constexpr int Bn = 2, Tn = 2048, Hn = 1024, NHn = 16, HDn = 64, HALFn = 32;
static constexpr int Mn = Bn * Tn;     // 4096
static constexpr int Kn = Hn;          // 1024
static constexpr int Nqkv = 3 * Hn;    // 3072

// async global->LDS, 16B per lane; dest must be linear-in-lane (rule #21)
__device__ __forceinline__ void gl16(const f16* g, f16* l) {
  __builtin_amdgcn_global_load_lds(
      (const __attribute__((address_space(1))) void*)g,
      (__attribute__((address_space(3))) void*)l, 16, 0, 0);
}

// ---------------- kernel: f32 -> f16 convert (vectorized, unchanged) --------
__global__ void k_convert(const float* __restrict__ in, f16* __restrict__ out, int n4) {
  int i = blockIdx.x * blockDim.x + threadIdx.x;
  if (i >= n4) return;
  float4 v = ((const float4*)in)[i];
  f16x4 o = { (f16)v.x, (f16)v.y, (f16)v.z, (f16)v.w };
  ((f16x4*)out)[i] = o;
}

// ------- transpose+convert W[Kr][Nc] f32 -> WT[Nc][Kr] f16 (unchanged) ------
__global__ void k_transpose(const float* __restrict__ W, f16* __restrict__ WT,
                            int Nc, int Kr) {
  const int wave = threadIdx.x >> 6, lane = threadIdx.x & 63;
  const int n  = blockIdx.x * 32 + wave * 8 + (lane >> 3);
  const int k0 = blockIdx.y * 64 + (lane & 7) * 8;
  f16x8 v;
#pragma unroll
  for (int j = 0; j < 8; ++j) v[j] = (f16)W[(size_t)(k0 + j) * Nc + n];
  *(f16x8*)(WT + (size_t)n * Kr + k0) = v;
}

// ---------------- GEMM (unchanged from round 7/11) ---------------------------
template <int EPI>
__global__ __launch_bounds__(256) void k_gemm(
    const f16* __restrict__ A, const f16* __restrict__ BT,
    const float* __restrict__ rc, const float* __restrict__ rs,
    const float* __restrict__ bias,
    f16* __restrict__ qo, f16* __restrict__ ko, f16* __restrict__ vto,
    float* __restrict__ out, int Kd) {
  __shared__ f16 smem[16384];          // Af 128x64 | Bf 128x64 (32 KB)
  f16* Af = smem;
  f16* Bf = smem + 8192;
  const int tid = threadIdx.x;
  const int wave = tid >> 6, lane = tid & 63;
  const int lr = lane & 15, lg = lane >> 4;
  const int m0 = blockIdx.x * 128, n0 = blockIdx.y * 128;
  const int wm = (wave & 1) * 64, wn = (wave >> 1) * 64;
  const int lane8 = lane >> 3;         // row within 8-row staging group
  const int sc = lane & 7;             // linear dest 16B chunk

  f32x4 acc[4][4] = {};

  for (int k0 = 0; k0 < Kd; k0 += 64) {
    __syncthreads();
#pragma unroll
    for (int i = 0; i < 4; ++i) {
      int r = wave * 32 + i * 8 + lane8;
      int csrc = sc ^ (r & 7);         // pre-swizzled global chunk
      gl16(A  + (size_t)(m0 + r) * Kd + k0 + csrc * 8, Af + r * 64 + sc * 8);
      gl16(BT + (size_t)(n0 + r) * Kd + k0 + csrc * 8, Bf + r * 64 + sc * 8);
    }
    __syncthreads();                   // drains vmcnt(0): LDS tiles ready
#pragma unroll
    for (int kf = 0; kf < 2; ++kf) {
      f16x8 af[4], bf[4];
#pragma unroll
      for (int mi = 0; mi < 4; ++mi) {
        int row = wm + mi * 16 + lr;
        af[mi] = *(const f16x8*)(Af + row * 64 + (((kf * 4 + lg) ^ (row & 7)) * 8));
      }
#pragma unroll
      for (int ni = 0; ni < 4; ++ni) {
        int row = wn + ni * 16 + lr;
        bf[ni] = *(const f16x8*)(Bf + row * 64 + (((kf * 4 + lg) ^ (row & 7)) * 8));
      }
#pragma unroll
      for (int mi = 0; mi < 4; ++mi)
#pragma unroll
        for (int ni = 0; ni < 4; ++ni)
          acc[mi][ni] = __builtin_amdgcn_mfma_f32_16x16x32_f16(af[mi], bf[ni], acc[mi][ni], 0, 0, 0);
    }
  }

  if (EPI == 1) {
#pragma unroll
    for (int mi = 0; mi < 4; ++mi)
#pragma unroll
      for (int ni = 0; ni < 4; ++ni) {
        int col = n0 + wn + ni * 16 + lr;
        float bv = bias[col];
#pragma unroll
        for (int r = 0; r < 4; ++r) {
          int grow = m0 + wm + mi * 16 + lg * 4 + r;
          out[(size_t)grow * Hn + col] = acc[mi][ni][r] + bv;
        }
      }
    return;
  }

  const int part = n0 >> 10;
  if (part < 2) {
    f16* dst = (part == 0) ? qo : ko;
    const float scale = (part == 0) ? 0.125f : 1.0f;  // HD^-0.5 folded into q
#pragma unroll
    for (int mi = 0; mi < 4; ++mi)
#pragma unroll
      for (int ni = 0; ni < 4; ++ni) {
        int col = n0 + wn + ni * 16 + lr;
        int hn = (col >> 6) & 15, d = col & 63;
#pragma unroll
        for (int r = 0; r < 4; ++r) {
          int grow = m0 + wm + mi * 16 + lg * 4 + r;
          int b = grow >> 11, t = grow & (Tn - 1);
          float v = acc[mi][ni][r];
          float vp = __shfl_xor(v, 1);  // partner column (d^1) lives in lane^1
          float cc = rc[t * HALFn + (d >> 1)];
          float ss = rs[t * HALFn + (d >> 1)];
          float res = (d & 1) ? (ss * vp + cc * v) : (cc * v - ss * vp);
          res *= scale;
          dst[(((size_t)(b * NHn + hn)) * Tn + t) * HDn + d] = (f16)res;
        }
      }
  } else {
    // V: write transposed [b,h,d,t] via LDS bounce
    __syncthreads();
#pragma unroll
    for (int mi = 0; mi < 4; ++mi)
#pragma unroll
      for (int ni = 0; ni < 4; ++ni) {
        int dl = wn + ni * 16 + lr;
#pragma unroll
        for (int r = 0; r < 4; ++r) {
          int tl = wm + mi * 16 + lg * 4 + r;
          smem[tl * 128 + dl] = (f16)acc[mi][ni][r];
        }
      }
    __syncthreads();
    int b = m0 >> 11, t0 = m0 & (Tn - 1);
    int hbase = (n0 & 1023) >> 6;
#pragma unroll
    for (int it = 0; it < 8; ++it) {
      int slot = tid + it * 256;
      int d = slot >> 4, tc = slot & 15;
      f16x8 v;
#pragma unroll
      for (int j = 0; j < 8; ++j) v[j] = smem[(tc * 8 + j) * 128 + d];
      int hh = hbase + (d >> 6), dc = d & 63;
      *(f16x8*)(vto + (((size_t)(b * NHn + hh)) * HDn + dc) * Tn + t0 + tc * 8) = v;
    }
  }
}

// -------- flash attention: 32 q-rows/wave (validated) + T14 async-STAGE ------
// grid (T/128, B*NH). K/V double-buffered in LDS (48 KB total); tile t+1's
// global loads are issued BEFORE compute of tile t (regs), ds_write lands them
// after the next barrier — staging latency hides under QK^T/softmax/PV.
__global__ __launch_bounds__(256) void k_attn(
    const f16* __restrict__ Q, const f16* __restrict__ Kk,
    const f16* __restrict__ VT, f16* __restrict__ O) {
  __shared__ f16 Kl[2][64 * 64];
  __shared__ f16 Vl[2][64 * 64];  // V^T tile: [d][kv]
  __shared__ f16 Pl[4][32 * 64];  // per-wave P [q][kv]; reused as O-bounce [q][d]
  const int tid = threadIdx.x;
  const int wave = tid >> 6, lane = tid & 63;
  const int lr = lane & 15, lg = lane >> 4;
  const int bh = blockIdx.y;
  const int q0 = blockIdx.x * 128;
  const f16* qb = Q + (size_t)bh * (Tn * HDn);
  const f16* kb = Kk + (size_t)bh * (Tn * HDn);
  const f16* vb = VT + (size_t)bh * (HDn * Tn);
  f16* Pw = Pl[wave];
  const int srow = tid >> 3, sc8 = tid & 7;        // staging slot 0 (slot 1 = +32 rows)

  f16x8 qf[2][2];
#pragma unroll
  for (int qi = 0; qi < 2; ++qi)
#pragma unroll
    for (int h = 0; h < 2; ++h)
      qf[qi][h] = *(const f16x8*)(qb + (size_t)(q0 + wave * 32 + qi * 16 + lr) * HDn + h * 32 + lg * 8);

  f32x4 o[4][2] = {};          // O^T: row d=di*16+lg*4+r, col q=qi*16+lr
  float m[2] = {-1e30f, -1e30f};
  float l[2] = {0.f, 0.f};     // lane-partial row sums (reduced across lg at end)

  // prefetch tile 0 into regs
  f16x8 kr[2], vr[2];
#pragma unroll
  for (int it = 0; it < 2; ++it) {
    int row = srow + it * 32;
    kr[it] = *(const f16x8*)(kb + (size_t)row * HDn + sc8 * 8);
    vr[it] = *(const f16x8*)(vb + (size_t)row * Tn + sc8 * 8);
  }

  for (int kt = 0; kt < Tn / 64; ++kt) {
    const int cur = kt & 1;
    f16* Klc = Kl[cur];
    f16* Vlc = Vl[cur];
    __syncthreads();             // buf[cur]'s previous consumers (kt-2) done
#pragma unroll
    for (int it = 0; it < 2; ++it) {
      int row = srow + it * 32;
      *(f16x8*)(Klc + row * 64 + ((sc8 ^ (row & 7)) * 8)) = kr[it];
      *(f16x8*)(Vlc + row * 64 + ((sc8 ^ (row & 7)) * 8)) = vr[it];
    }
    // issue next tile's loads now; they complete under this tile's compute
    if (kt + 1 < Tn / 64) {
#pragma unroll
      for (int it = 0; it < 2; ++it) {
        int row = srow + it * 32;
        kr[it] = *(const f16x8*)(kb + (size_t)((kt + 1) * 64 + row) * HDn + sc8 * 8);
        vr[it] = *(const f16x8*)(vb + (size_t)row * Tn + (kt + 1) * 64 + sc8 * 8);
      }
    }
    __syncthreads();             // buf[cur] ready

    // S^T = K Q^T (row=kv, col=q); q pre-scaled by 1/8 in k_gemm<0>
    f32x4 s[4][2];
#pragma unroll
    for (int kvi = 0; kvi < 4; ++kvi) {
      int row = kvi * 16 + lr;
      f16x8 kf0 = *(const f16x8*)(Klc + row * 64 + ((lg ^ (row & 7)) * 8));
      f16x8 kf1 = *(const f16x8*)(Klc + row * 64 + (((4 + lg) ^ (row & 7)) * 8));
#pragma unroll
      for (int qi = 0; qi < 2; ++qi) {
        f32x4 t = {0.f, 0.f, 0.f, 0.f};
        t = __builtin_amdgcn_mfma_f32_16x16x32_f16(kf0, qf[qi][0], t, 0, 0, 0);
        t = __builtin_amdgcn_mfma_f32_16x16x32_f16(kf1, qf[qi][1], t, 0, 0, 0);
        s[kvi][qi] = t;
      }
    }

    // defer-max online softmax: in-thread tile max, rescale only when it grows
    float pm[2];
#pragma unroll
    for (int qi = 0; qi < 2; ++qi) {
      f32x4 m4 = s[0][qi];
#pragma unroll
      for (int kvi = 1; kvi < 4; ++kvi) {
        m4[0] = fmaxf(m4[0], s[kvi][qi][0]); m4[1] = fmaxf(m4[1], s[kvi][qi][1]);
        m4[2] = fmaxf(m4[2], s[kvi][qi][2]); m4[3] = fmaxf(m4[3], s[kvi][qi][3]);
      }
      pm[qi] = fmaxf(fmaxf(m4[0], m4[1]), fmaxf(m4[2], m4[3]));
    }
    if (!__all(pm[0] <= m[0] + 8.f && pm[1] <= m[1] + 8.f)) {
#pragma unroll
      for (int qi = 0; qi < 2; ++qi) {
        float mx = pm[qi];
        mx = fmaxf(mx, __shfl_xor(mx, 16));
        mx = fmaxf(mx, __shfl_xor(mx, 32));
        float mnew = fmaxf(m[qi], mx);
        float alpha = __expf(m[qi] - mnew);
        m[qi] = mnew;
        l[qi] *= alpha;
#pragma unroll
        for (int di = 0; di < 4; ++di) {
          o[di][qi][0] *= alpha; o[di][qi][1] *= alpha;
          o[di][qi][2] *= alpha; o[di][qi][3] *= alpha;
        }
      }
    }

    // exp + partial row sum + packed P write (8B words, kv contiguous over r)
#pragma unroll
    for (int qi = 0; qi < 2; ++qi) {
      int q = qi * 16 + lr;
      float rsum = 0.f;
#pragma unroll
      for (int kvi = 0; kvi < 4; ++kvi) {
        f16x4 w;
#pragma unroll
        for (int r = 0; r < 4; ++r) {
          float p = __expf(s[kvi][qi][r] - m[qi]);
          rsum += p;
          w[r] = (f16)p;
        }
        int byteoff = (kvi * 32 + lg * 8) ^ ((q & 7) << 4);
        *(f16x4*)(Pw + q * 64 + (byteoff >> 1)) = w;
      }
      l[qi] += rsum;
    }

    // O^T += V^T · P  (A = V^T rows d, B = P cols q, K = kv)
#pragma unroll
    for (int h = 0; h < 2; ++h) {
      f16x8 pb[2], va[4];
#pragma unroll
      for (int qi = 0; qi < 2; ++qi) {
        int q = qi * 16 + lr;
        int byteoff = (h * 64 + lg * 16) ^ ((q & 7) << 4);
        pb[qi] = *(const f16x8*)(Pw + q * 64 + (byteoff >> 1));
      }
#pragma unroll
      for (int di = 0; di < 4; ++di) {
        int row = di * 16 + lr;
        va[di] = *(const f16x8*)(Vlc + row * 64 + (((h * 4 + lg) ^ (row & 7)) * 8));
      }
#pragma unroll
      for (int di = 0; di < 4; ++di)
#pragma unroll
        for (int qi = 0; qi < 2; ++qi)
          o[di][qi] = __builtin_amdgcn_mfma_f32_16x16x32_f16(va[di], pb[qi], o[di][qi], 0, 0, 0);
    }
  }

  // finalize: reduce lane-partial l across lg, scale, transpose via LDS bounce
  float inv[2];
#pragma unroll
  for (int qi = 0; qi < 2; ++qi) {
    float lf = l[qi];
    lf += __shfl_xor(lf, 16);
    lf += __shfl_xor(lf, 32);
    inv[qi] = 1.f / lf;
  }
#pragma unroll
  for (int qi = 0; qi < 2; ++qi) {
    int q = qi * 16 + lr;
#pragma unroll
    for (int di = 0; di < 4; ++di) {
      f16x4 w;
#pragma unroll
      for (int r = 0; r < 4; ++r) w[r] = (f16)(o[di][qi][r] * inv[qi]);
      int byteoff = (di * 32 + lg * 8) ^ ((q & 7) << 4);
      *(f16x4*)(Pw + q * 64 + (byteoff >> 1)) = w;
    }
  }
  const int b = bh >> 4, h = bh & 15;
#pragma unroll
  for (int it = 0; it < 4; ++it) {
    int row = it * 8 + (lane >> 3);   // local q 0..31
    int c = lane & 7;                 // 16B chunk of the 64-d row
    int byteoff = (c * 16) ^ ((row & 7) << 4);
    f16x8 v = *(const f16x8*)(Pw + row * 64 + (byteoff >> 1));
    int t = q0 + wave * 32 + row;
    *(f16x8*)(O + ((size_t)(b * Tn + t)) * Hn + h * HDn + c * 8) = v;
  }
}

// ---------------- launch ----------------------------------------------------
extern "C" void kernel_launch(void* const* d_in, const int* in_sizes, int n_in,
                              void* d_out, int out_size, void* d_ws, size_t ws_size,
                              hipStream_t stream) {
  const float* x     = (const float*)d_in[0];
  const float* wqkv  = (const float*)d_in[1];
  const float* wproj = (const float*)d_in[2];
  const float* bproj = (const float*)d_in[3];
  const float* rc    = (const float*)d_in[4];
  const float* rs    = (const float*)d_in[5];
  float* out = (float*)d_out;

  char* ws = (char*)d_ws;
  f16* Xh  = (f16*)(ws);                    // 8 MB  [4096][1024]
  f16* WqT = (f16*)(ws + (8u << 20));       // 6 MB  [3072][1024]
  f16* WpT = (f16*)(ws + (14u << 20));      // 2 MB  [1024][1024]
  f16* Qw  = (f16*)(ws + (16u << 20));      // 8 MB  [32][2048][64]
  f16* Kw  = (f16*)(ws + (24u << 20));      // 8 MB
  f16* Vw  = (f16*)(ws + (32u << 20));      // 8 MB  [32][64][2048]  (transposed)
  f16* Ao  = (f16*)(ws + (40u << 20));      // 8 MB  [4096][1024]

  k_convert<<<(Mn * Kn / 4 + 255) / 256, 256, 0, stream>>>(x, Xh, Mn * Kn / 4);
  k_transpose<<<dim3(Nqkv / 32, Kn / 64), 256, 0, stream>>>(wqkv, WqT, Nqkv, Kn);
  k_transpose<<<dim3(Hn / 32, Kn / 64), 256, 0, stream>>>(wproj, WpT, Hn, Kn);
  k_gemm<0><<<dim3(Mn / 128, Nqkv / 128), 256, 0, stream>>>(
      Xh, WqT, rc, rs, nullptr, Qw, Kw, Vw, nullptr, Kn);
  k_attn<<<dim3(Tn / 128, Bn * NHn), 256, 0, stream>>>(Qw, Kw, Vw, Ao);
  k_gemm<1><<<dim3(Mn / 128, Hn / 128), 256, 0, stream>>>(
      Ao, WpT, nullptr, nullptr, bproj, nullptr, nullptr, nullptr, out, Kn);
}